// Round 10
// baseline (114.283 us; speedup 1.0000x reference)
//
#include <hip/hip_runtime.h>
#include <hip/hip_fp16.h>

#define S_LEN 8192
#define T_LEN 8192
#define D_DIM 256
#define QBLK 64
#define KVBLK 32
#define TSPLIT 4
#define NKV ((T_LEN / TSPLIT) / KVBLK)  // 64 tiles per block
#define NQT (S_LEN / QBLK)              // 128
#define KTILE_BYTES 16384               // 32 keys x 256 d x 2B (linear-read image)
#define VTILE_BYTES 16384               // 256 d x 32 keys x 2B (linear-read image)
#define RESCALE_THR 6.0f                // log2 domain
#define LOG2E 1.44269504f
// LDS map (dynamic, 75776 B/block -> 2 blocks/CU of 160KB):
//   sK  2 x 16KB @ 0      sV 2 x 16KB @ 32768
//   sPu 2 x 4KB  @ 65536  (buf*4096 + pw*2048 + mi*1024 + lane*16)
//   sSc 2 x 1KB  @ 73728  (buf*1024 + pw*512 + lane*8)
#define SMEM_BYTES 75776

typedef _Float16 f16x8 __attribute__((ext_vector_type(8)));
typedef float f32x4 __attribute__((ext_vector_type(4)));

struct h4 { _Float16 h[4]; };

#define GLOAD_LDS16(g, l)                                              \
    __builtin_amdgcn_global_load_lds(                                  \
        (const __attribute__((address_space(1))) void*)(g),            \
        (__attribute__((address_space(3))) void*)(l), 16, 0, 0)

#define MFMA16(a, b, c) __builtin_amdgcn_mfma_f32_16x16x32_f16(a, b, c, 0, 0, 0)

#if __has_builtin(__builtin_amdgcn_exp2f)
#define EXP2(x) __builtin_amdgcn_exp2f(x)
#else
static __device__ __forceinline__ float EXP2(float x) {
    float y;
    asm("v_exp_f32 %0, %1" : "=v"(y) : "v"(x));
    return y;
}
#endif

// ---------------- Q: fp32 -> f16 row-major, pre-scaled by log2(e) ----------------
__global__ __launch_bounds__(256) void cvt_kernel(const float* __restrict__ in,
                                                  _Float16* __restrict__ out, int n4) {
    int i = blockIdx.x * 256 + threadIdx.x;
    if (i < n4) {
        float4 v = ((const float4*)in)[i];
        h4 o;
        o.h[0] = (_Float16)(v.x * LOG2E); o.h[1] = (_Float16)(v.y * LOG2E);
        o.h[2] = (_Float16)(v.z * LOG2E); o.h[3] = (_Float16)(v.w * LOG2E);
        ((h4*)out)[i] = o;
    }
}

// ------- K -> Kimg. Granule (row r, gr) of tile t (gr=dim/8, ks=gr>>2, g=gr&3)
// at ks*2048 + (r>>4)*1024 + (r&15)*64 + g*16 -> QK step reads are contiguous
// 1KB wave-reads (conflict-free, no swizzle VALU). -------
__global__ __launch_bounds__(256) void cvt_swz_kernel(const float* __restrict__ in,
                                                      _Float16* __restrict__ img,
                                                      int nchunks) {
    int id = blockIdx.x * 256 + threadIdx.x;
    if (id >= nchunks) return;
    int row = id >> 5, gr = id & 31;
    int t = row >> 5, r = row & 31;
    float4 a = *(const float4*)(in + (size_t)row * D_DIM + gr * 8);
    float4 b = *(const float4*)(in + (size_t)row * D_DIM + gr * 8 + 4);
    f16x8 o;
    o[0] = (_Float16)a.x; o[1] = (_Float16)a.y; o[2] = (_Float16)a.z; o[3] = (_Float16)a.w;
    o[4] = (_Float16)b.x; o[5] = (_Float16)b.y; o[6] = (_Float16)b.z; o[7] = (_Float16)b.w;
    *(f16x8*)((char*)img + (size_t)t * KTILE_BYTES + (gr >> 2) * 2048 +
              ((r >> 4) << 10) + ((r & 15) << 6) + ((gr & 3) << 4)) = o;
}

// ------- V -> Vimg. Granule (d, gk) holds keys pi(gk*8+j)=(j>>2)*16+gk*4+(j&3),
// at (d>>4)*1024 + gk*256 + (d&15)*16 -> PV read addr = dt*1024 + lane*16. -------
__global__ __launch_bounds__(256) void vt_swz_kernel(const float* __restrict__ V,
                                                     _Float16* __restrict__ Vimg) {
    __shared__ float tile[32][260];
    const int t = blockIdx.x;
#pragma unroll
    for (int i = 0; i < 8; ++i) {
        int idx = i * 256 + threadIdx.x;
        int kr = idx >> 6, c4 = idx & 63;
        float4 v = *(const float4*)(V + ((size_t)t * 32 + kr) * D_DIM + c4 * 4);
        tile[kr][c4 * 4 + 0] = v.x;
        tile[kr][c4 * 4 + 1] = v.y;
        tile[kr][c4 * 4 + 2] = v.z;
        tile[kr][c4 * 4 + 3] = v.w;
    }
    __syncthreads();
#pragma unroll
    for (int i = 0; i < 4; ++i) {
        int gid = i * 256 + threadIdx.x;
        int d = gid >> 2, gk = gid & 3;
        f16x8 o;
#pragma unroll
        for (int j = 0; j < 8; ++j)
            o[j] = (_Float16)tile[(j >> 2) * 16 + gk * 4 + (j & 3)][d];
        *(f16x8*)((char*)Vimg + (size_t)t * VTILE_BYTES + ((d >> 4) << 10) +
                  (gk << 8) + ((d & 15) << 4)) = o;
    }
}

// ---------------- flash attention: producer/consumer wave specialization ----------
// waves 0,1 = PRODUCERS (QK^T + softmax; read only K; write P-frags to LDS),
// waves 2,3 = CONSUMERS (PV; read only V + P-frags; own the O accumulator).
// Identity lane handoff: consumer lane l runs the exact PV MFMA producer lane l
// would have. LDS bytes per block-tile: 68KB reads vs 128KB before (the 4x K/V
// read redundancy was the measured bottleneck: 7100 LDS-cyc per 7000-cyc tile).
// Separate loops per role -> qf/st (producer) and acc (consumer) liveness never
// overlaps -> both roles have big VGPR headroom for ds_read hoisting.
__global__ __launch_bounds__(256, 2) void attn_kernel(
    const _Float16* __restrict__ Qh, const _Float16* __restrict__ Kimg,
    const _Float16* __restrict__ Vimg, _Float16* __restrict__ Opart,
    float* __restrict__ ml) {
    extern __shared__ __align__(16) char smem[];
    char* sK = smem;
    char* sV = smem + 32768;
    char* sPu = smem + 65536;
    char* sSc = smem + 73728;

    const int tid = threadIdx.x;
    const int wave = tid >> 6, lane = tid & 63;
    const int g = lane >> 4, c = lane & 15;
    const int bid = blockIdx.x;
    const int qtile = bid >> 2, split = bid & 3;
    const int tile0 = split * NKV;
    // stagger: co-resident blocks (bid, bid+256 -> qtile+64) start 32 tiles apart
    const int rot = ((qtile >> 6) << 5) | ((qtile & 7) << 2);

    if (wave < 2) {
        // ================= PRODUCER =================
        f16x8 qf[2][8];
        {
            const size_t qrow0 = (size_t)qtile * QBLK + wave * 32 + c;
#pragma unroll
            for (int mi = 0; mi < 2; ++mi)
#pragma unroll
                for (int ks = 0; ks < 8; ++ks)
                    qf[mi][ks] = *(const f16x8*)(Qh + (qrow0 + mi * 16) * D_DIM +
                                                 (ks * 4 + g) * 8);
        }
        asm volatile("s_waitcnt vmcnt(0)" ::: "memory");  // qf out of vmcnt counting

        // prologue: stage K(0)
        {
            const char* Kt =
                (const char*)Kimg + (size_t)(tile0 + rot) * KTILE_BYTES;
#pragma unroll
            for (int i = 0; i < 8; ++i)
                GLOAD_LDS16(Kt + i * 2048 + tid * 16, sK + i * 2048 + tid * 16);
        }

        const int kbase = (c << 6) | (g << 4);
        float m[2] = {-1e30f, -1e30f};
        float l[2] = {0.f, 0.f};

        for (int kt = 0; kt < NKV; ++kt) {
            asm volatile("s_waitcnt vmcnt(0)" ::: "memory");  // K(kt) landed (aged 1 iter)
            __builtin_amdgcn_s_barrier();                     // B1: K(kt) visible
            if (kt + 1 < NKV) {
                const int tn = tile0 + ((kt + 1 + rot) & (NKV - 1));
                const char* Kt = (const char*)Kimg + (size_t)tn * KTILE_BYTES;
                const int nb = ((kt + 1) & 1) * 16384;
#pragma unroll
                for (int i = 0; i < 8; ++i)
                    GLOAD_LDS16(Kt + i * 2048 + tid * 16, sK + nb + i * 2048 + tid * 16);
            }
            const char* sKb = sK + (kt & 1) * 16384;

            // QK^T swapped: st[mi][ct] = S^T[key=ct*16+g*4+r][q=mi*16+c]
            f32x4 st[2][2];
#pragma unroll
            for (int mi = 0; mi < 2; ++mi)
#pragma unroll
                for (int ct = 0; ct < 2; ++ct) st[mi][ct] = (f32x4){0.f, 0.f, 0.f, 0.f};
            __builtin_amdgcn_s_setprio(1);
#pragma unroll
            for (int ks = 0; ks < 8; ++ks) {
                f16x8 kf0 = *(const f16x8*)(sKb + ks * 2048 + kbase);
                f16x8 kf1 = *(const f16x8*)(sKb + ks * 2048 + 1024 + kbase);
                st[0][0] = MFMA16(kf0, qf[0][ks], st[0][0]);
                st[0][1] = MFMA16(kf1, qf[0][ks], st[0][1]);
                st[1][0] = MFMA16(kf0, qf[1][ks], st[1][0]);
                st[1][1] = MFMA16(kf1, qf[1][ks], st[1][1]);
            }
            __builtin_amdgcn_s_setprio(0);

            // online softmax (base-2); pack P in-lane (pi-permuted V absorbs order)
            float sc[2];
            uint4 pu[2];
#pragma unroll
            for (int mi = 0; mi < 2; ++mi) {
                float pm = fmaxf(fmaxf(fmaxf(st[mi][0][0], st[mi][0][1]),
                                       fmaxf(st[mi][0][2], st[mi][0][3])),
                                 fmaxf(fmaxf(st[mi][1][0], st[mi][1][1]),
                                       fmaxf(st[mi][1][2], st[mi][1][3])));
                sc[mi] = 1.0f;
                if (__any(pm > m[mi] + RESCALE_THR)) {
                    pm = fmaxf(pm, __shfl_xor(pm, 16));
                    pm = fmaxf(pm, __shfl_xor(pm, 32));
                    float mn = fmaxf(m[mi], pm);
                    sc[mi] = EXP2(m[mi] - mn);
                    m[mi] = mn;
                    l[mi] *= sc[mi];
                }
                float rs = 0.f;
#pragma unroll
                for (int ct = 0; ct < 2; ++ct)
#pragma unroll
                    for (int r = 0; r < 4; ++r) {
                        float p = EXP2(st[mi][ct][r] - m[mi]);
                        st[mi][ct][r] = p;
                        rs += p;
                    }
                l[mi] += rs;  // per-lane partial; reduced at epilogue
                pu[mi].x = __builtin_bit_cast(
                    unsigned int, __builtin_amdgcn_cvt_pkrtz(st[mi][0][0], st[mi][0][1]));
                pu[mi].y = __builtin_bit_cast(
                    unsigned int, __builtin_amdgcn_cvt_pkrtz(st[mi][0][2], st[mi][0][3]));
                pu[mi].z = __builtin_bit_cast(
                    unsigned int, __builtin_amdgcn_cvt_pkrtz(st[mi][1][0], st[mi][1][1]));
                pu[mi].w = __builtin_bit_cast(
                    unsigned int, __builtin_amdgcn_cvt_pkrtz(st[mi][1][2], st[mi][1][3]));
            }

            // hand off P-frags + rescale factors (identity lane mapping)
            {
                char* pb = sPu + (kt & 1) * 4096 + wave * 2048;
                *(uint4*)(pb + lane * 16) = pu[0];
                *(uint4*)(pb + 1024 + lane * 16) = pu[1];
                *(float2*)(sSc + (kt & 1) * 1024 + wave * 512 + lane * 8) =
                    make_float2(sc[0], sc[1]);
            }
            asm volatile("s_waitcnt lgkmcnt(0)" ::: "memory");
            __builtin_amdgcn_sched_barrier(0);
            __builtin_amdgcn_s_barrier();  // B2: pu(kt)/sc(kt) published
        }

        // epilogue: finish deferred l reduction, write (m,l)
#pragma unroll
        for (int mi = 0; mi < 2; ++mi) {
            l[mi] += __shfl_xor(l[mi], 16);
            l[mi] += __shfl_xor(l[mi], 32);
        }
        if (g == 0) {
            float* mlb = ml + (size_t)((qtile * TSPLIT + split) * QBLK) * 2;
#pragma unroll
            for (int mi = 0; mi < 2; ++mi) {
                int row = wave * 32 + mi * 16 + c;
                mlb[row * 2 + 0] = m[mi];
                mlb[row * 2 + 1] = l[mi];
            }
        }
    } else {
        // ================= CONSUMER =================
        const int ctid = tid - 128;  // 0..127
        const int cw = wave - 2;     // partner producer wave
        f32x4 acc[2][16];
#pragma unroll
        for (int mi = 0; mi < 2; ++mi)
#pragma unroll
            for (int dt = 0; dt < 16; ++dt) acc[mi][dt] = (f32x4){0.f, 0.f, 0.f, 0.f};

        // prologue: stage V(0)
        {
            const char* Vt =
                (const char*)Vimg + (size_t)(tile0 + rot) * VTILE_BYTES;
#pragma unroll
            for (int i = 0; i < 8; ++i)
                GLOAD_LDS16(Vt + i * 2048 + ctid * 16, sV + i * 2048 + ctid * 16);
        }

        for (int kt = 0; kt < NKV; ++kt) {
            __builtin_amdgcn_s_barrier();  // B1
            if (kt > 0) {
                const int j = kt - 1;
                const char* sVb = sV + (j & 1) * 16384;
                const char* pb = sPu + (j & 1) * 4096 + cw * 2048;
                uint4 u0 = *(const uint4*)(pb + lane * 16);
                uint4 u1 = *(const uint4*)(pb + 1024 + lane * 16);
                float2 scv = *(const float2*)(sSc + (j & 1) * 1024 + cw * 512 + lane * 8);
                if (__any(scv.x != 1.0f)) {
                    float fr[4];
#pragma unroll
                    for (int r = 0; r < 4; ++r)
                        fr[r] = __shfl(scv.x, (g << 4) | (g * 4 + r));
#pragma unroll
                    for (int dt = 0; dt < 16; ++dt)
#pragma unroll
                        for (int r = 0; r < 4; ++r) acc[0][dt][r] *= fr[r];
                }
                if (__any(scv.y != 1.0f)) {
                    float fr[4];
#pragma unroll
                    for (int r = 0; r < 4; ++r)
                        fr[r] = __shfl(scv.y, (g << 4) | (g * 4 + r));
#pragma unroll
                    for (int dt = 0; dt < 16; ++dt)
#pragma unroll
                        for (int r = 0; r < 4; ++r) acc[1][dt][r] *= fr[r];
                }
                f16x8 p0 = __builtin_bit_cast(f16x8, u0);
                f16x8 p1 = __builtin_bit_cast(f16x8, u1);
                __builtin_amdgcn_s_setprio(1);
#pragma unroll
                for (int dt = 0; dt < 16; ++dt) {
                    f16x8 vf = *(const f16x8*)(sVb + dt * 1024 + lane * 16);
                    acc[0][dt] = MFMA16(p0, vf, acc[0][dt]);
                    acc[1][dt] = MFMA16(p1, vf, acc[1][dt]);
                }
                __builtin_amdgcn_s_setprio(0);
            }
            asm volatile("s_waitcnt vmcnt(0)" ::: "memory");  // V(kt) landed
            __builtin_amdgcn_s_barrier();                     // B2: V(kt) published
            if (kt + 1 < NKV) {
                const int tn = tile0 + ((kt + 1 + rot) & (NKV - 1));
                const char* Vt = (const char*)Vimg + (size_t)tn * VTILE_BYTES;
                const int nb = ((kt + 1) & 1) * 16384;
#pragma unroll
                for (int i = 0; i < 8; ++i)
                    GLOAD_LDS16(Vt + i * 2048 + ctid * 16, sV + nb + i * 2048 + ctid * 16);
            }
        }

        // final PV(NKV-1)
        {
            const int j = NKV - 1;
            const char* sVb = sV + (j & 1) * 16384;
            const char* pb = sPu + (j & 1) * 4096 + cw * 2048;
            uint4 u0 = *(const uint4*)(pb + lane * 16);
            uint4 u1 = *(const uint4*)(pb + 1024 + lane * 16);
            float2 scv = *(const float2*)(sSc + (j & 1) * 1024 + cw * 512 + lane * 8);
            if (__any(scv.x != 1.0f)) {
                float fr[4];
#pragma unroll
                for (int r = 0; r < 4; ++r) fr[r] = __shfl(scv.x, (g << 4) | (g * 4 + r));
#pragma unroll
                for (int dt = 0; dt < 16; ++dt)
#pragma unroll
                    for (int r = 0; r < 4; ++r) acc[0][dt][r] *= fr[r];
            }
            if (__any(scv.y != 1.0f)) {
                float fr[4];
#pragma unroll
                for (int r = 0; r < 4; ++r) fr[r] = __shfl(scv.y, (g << 4) | (g * 4 + r));
#pragma unroll
                for (int dt = 0; dt < 16; ++dt)
#pragma unroll
                    for (int r = 0; r < 4; ++r) acc[1][dt][r] *= fr[r];
            }
            f16x8 p0 = __builtin_bit_cast(f16x8, u0);
            f16x8 p1 = __builtin_bit_cast(f16x8, u1);
#pragma unroll
            for (int dt = 0; dt < 16; ++dt) {
                f16x8 vf = *(const f16x8*)(sVb + dt * 1024 + lane * 16);
                acc[0][dt] = MFMA16(p0, vf, acc[0][dt]);
                acc[1][dt] = MFMA16(p1, vf, acc[1][dt]);
            }
        }

        // epilogue: unnormalized partial O (f16)
        _Float16* Ob = Opart + (size_t)(qtile * TSPLIT + split) * QBLK * D_DIM;
#pragma unroll
        for (int mi = 0; mi < 2; ++mi)
#pragma unroll
            for (int dt = 0; dt < 16; ++dt)
#pragma unroll
                for (int r = 0; r < 4; ++r) {
                    int row = cw * 32 + mi * 16 + g * 4 + r;
                    int col = dt * 16 + c;
                    Ob[(size_t)row * D_DIM + col] = (_Float16)acc[mi][dt][r];
                }
    }
}

// ---------------- combine TSPLIT partials (base-2 stats) ----------------
__global__ __launch_bounds__(256) void combine_kernel(const _Float16* __restrict__ Opart,
                                                      const float* __restrict__ ml,
                                                      float* __restrict__ out) {
    int r = blockIdx.x;
    int qtile = r >> 6, rl = r & 63;  // QBLK=64
    int d = threadIdx.x;
    float mv[TSPLIT], lv[TSPLIT];
    float M = -1e30f;
#pragma unroll
    for (int s = 0; s < TSPLIT; ++s) {
        const float* mlb = ml + (size_t)((qtile * TSPLIT + s) * QBLK + rl) * 2;
        mv[s] = mlb[0];
        lv[s] = mlb[1];
        M = fmaxf(M, mv[s]);
    }
    float num = 0.f, den = 0.f;
#pragma unroll
    for (int s = 0; s < TSPLIT; ++s) {
        float w = EXP2(mv[s] - M);
        num += w * (float)Opart[((size_t)(qtile * TSPLIT + s) * QBLK + rl) * D_DIM + d];
        den += w * lv[s];
    }
    out[(size_t)r * D_DIM + d] = num / den;
}

extern "C" void kernel_launch(void* const* d_in, const int* in_sizes, int n_in,
                              void* d_out, int out_size, void* d_ws, size_t ws_size,
                              hipStream_t stream) {
    const float* Q = (const float*)d_in[0];
    const float* K = (const float*)d_in[1];
    const float* V = (const float*)d_in[2];
    float* out = (float*)d_out;
    char* ws = (char*)d_ws;

    _Float16* Qh = (_Float16*)ws;                    // 4MB row-major f16 (x log2e)
    _Float16* Kimg = (_Float16*)(ws + (4 << 20));    // 4MB linear-read 32-key tiles
    _Float16* Vimg = (_Float16*)(ws + (8 << 20));    // 4MB linear-read transposed tiles
    _Float16* Opart = (_Float16*)(ws + (12 << 20));  // 16MB f16 partials (TSPLIT=4)
    float* ml = (float*)(ws + ((size_t)28 << 20));   // 256KB

    const int n4 = S_LEN * D_DIM / 4;
    const int nchunks = S_LEN * D_DIM / 8;
    cvt_kernel<<<n4 / 256, 256, 0, stream>>>(Q, Qh, n4);
    cvt_swz_kernel<<<nchunks / 256, 256, 0, stream>>>(K, Kimg, nchunks);
    vt_swz_kernel<<<T_LEN / 32, 256, 0, stream>>>(V, Vimg);

    // 512 blocks x 256 thr, 74KB dyn LDS -> exactly 2 blocks/CU; bid&3 = split
    attn_kernel<<<NQT * TSPLIT, 256, SMEM_BYTES, stream>>>(Qh, Kimg, Vimg, Opart, ml);
    combine_kernel<<<S_LEN, 256, 0, stream>>>(Opart, ml, out);
}

// Round 11
// 107.613 us; speedup vs baseline: 1.0620x; 1.0620x over previous
//
#include <hip/hip_runtime.h>
#include <hip/hip_fp16.h>

#define S_LEN 8192
#define T_LEN 8192
#define D_DIM 256
#define QBLK 128
#define KVBLK 32
#define TSPLIT 8
#define NKV ((T_LEN / TSPLIT) / KVBLK)  // 32 tiles per block
#define NQT (S_LEN / QBLK)              // 64
#define KTILE_BYTES 16384               // 32 keys x 256 d x 2B (linear-read image)
#define VTILE_BYTES 16384               // 256 d x 32 keys x 2B (linear-read image)
#define RESCALE_THR 6.0f                // log2 domain
#define LOG2E 1.44269504f
// LDS: Kb 2x16KB @0 ; Vb 3x16KB @32768  -> 81920 B = exactly 160KB/2 -> 2 blocks/CU
#define SMEM_BYTES 81920

typedef _Float16 f16x8 __attribute__((ext_vector_type(8)));
typedef float f32x4 __attribute__((ext_vector_type(4)));

struct h4 { _Float16 h[4]; };

#define GLOAD_LDS16(g, l)                                              \
    __builtin_amdgcn_global_load_lds(                                  \
        (const __attribute__((address_space(1))) void*)(g),            \
        (__attribute__((address_space(3))) void*)(l), 16, 0, 0)

#define MFMA16(a, b, c) __builtin_amdgcn_mfma_f32_16x16x32_f16(a, b, c, 0, 0, 0)

#if __has_builtin(__builtin_amdgcn_exp2f)
#define EXP2(x) __builtin_amdgcn_exp2f(x)
#else
static __device__ __forceinline__ float EXP2(float x) {
    float y;
    asm("v_exp_f32 %0, %1" : "=v"(y) : "v"(x));
    return y;
}
#endif

// ---------------- Q: fp32 -> f16 row-major, pre-scaled by log2(e) ----------------
__global__ __launch_bounds__(256) void cvt_kernel(const float* __restrict__ in,
                                                  _Float16* __restrict__ out, int n4) {
    int i = blockIdx.x * 256 + threadIdx.x;
    if (i < n4) {
        float4 v = ((const float4*)in)[i];
        h4 o;
        o.h[0] = (_Float16)(v.x * LOG2E); o.h[1] = (_Float16)(v.y * LOG2E);
        o.h[2] = (_Float16)(v.z * LOG2E); o.h[3] = (_Float16)(v.w * LOG2E);
        ((h4*)out)[i] = o;
    }
}

// ------- K -> Kimg. Granule (row r, gr) of tile t (gr=dim/8, ks=gr>>2, g=gr&3)
// at ks*2048 + (r>>4)*1024 + (r&15)*64 + g*16 -> QK step reads are contiguous
// 1KB wave-reads (conflict-free, no swizzle VALU). -------
__global__ __launch_bounds__(256) void cvt_swz_kernel(const float* __restrict__ in,
                                                      _Float16* __restrict__ img,
                                                      int nchunks) {
    int id = blockIdx.x * 256 + threadIdx.x;
    if (id >= nchunks) return;
    int row = id >> 5, gr = id & 31;
    int t = row >> 5, r = row & 31;
    float4 a = *(const float4*)(in + (size_t)row * D_DIM + gr * 8);
    float4 b = *(const float4*)(in + (size_t)row * D_DIM + gr * 8 + 4);
    f16x8 o;
    o[0] = (_Float16)a.x; o[1] = (_Float16)a.y; o[2] = (_Float16)a.z; o[3] = (_Float16)a.w;
    o[4] = (_Float16)b.x; o[5] = (_Float16)b.y; o[6] = (_Float16)b.z; o[7] = (_Float16)b.w;
    *(f16x8*)((char*)img + (size_t)t * KTILE_BYTES + (gr >> 2) * 2048 +
              ((r >> 4) << 10) + ((r & 15) << 6) + ((gr & 3) << 4)) = o;
}

// ------- V -> Vimg. Granule (d, gk) holds keys pi(gk*8+j)=(j>>2)*16+gk*4+(j&3),
// at (d>>4)*1024 + gk*256 + (d&15)*16 -> PV read addr = dt*1024 + lane*16. -------
__global__ __launch_bounds__(256) void vt_swz_kernel(const float* __restrict__ V,
                                                     _Float16* __restrict__ Vimg) {
    __shared__ float tile[32][260];
    const int t = blockIdx.x;
#pragma unroll
    for (int i = 0; i < 8; ++i) {
        int idx = i * 256 + threadIdx.x;
        int kr = idx >> 6, c4 = idx & 63;
        float4 v = *(const float4*)(V + ((size_t)t * 32 + kr) * D_DIM + c4 * 4);
        tile[kr][c4 * 4 + 0] = v.x;
        tile[kr][c4 * 4 + 1] = v.y;
        tile[kr][c4 * 4 + 2] = v.z;
        tile[kr][c4 * 4 + 3] = v.w;
    }
    __syncthreads();
#pragma unroll
    for (int i = 0; i < 4; ++i) {
        int gid = i * 256 + threadIdx.x;
        int d = gid >> 2, gk = gid & 3;
        f16x8 o;
#pragma unroll
        for (int j = 0; j < 8; ++j)
            o[j] = (_Float16)tile[(j >> 2) * 16 + gk * 4 + (j & 3)][d];
        *(f16x8*)((char*)Vimg + (size_t)t * VTILE_BYTES + ((d >> 4) << 10) +
                  (gk << 8) + ((d & 15) << 4)) = o;
    }
}

// ---------------- flash attention: R9 base + T15 cross-tile pipeline ----------------
// 4 waves x 32 q-rows (M_rep=2). Per tile the serial chain QK->softmax->PV is
// broken by interleaving softmax(kt) [VALU] with QK(kt+1) [MFMA] (independent
// registers; separate pipes). Requires K(kt+1) and V(kt) live simultaneously:
// K double-buffer + V TRIPLE-buffer (80KB LDS, 2 blocks/CU).
// Hazards: stage K(kt+2)->Kb[kt&1] (last read: QK(kt), iter kt-1, fenced by end
// barrier); stage V(kt+2)->Vb[(kt+2)%3] (last read: PV(kt-1)); publish barrier
// after counted vmcnt(8). R9's stagger + XCD-local splits kept.
__global__ __launch_bounds__(256, 2) void attn_kernel(
    const _Float16* __restrict__ Qh, const _Float16* __restrict__ Kimg,
    const _Float16* __restrict__ Vimg, _Float16* __restrict__ Opart,
    float* __restrict__ ml) {
    extern __shared__ __align__(16) char smem[];
    char* sK = smem;          // 2 x 16KB
    char* sV = smem + 32768;  // 3 x 16KB
    const int tid = threadIdx.x;
    const int wave = tid >> 6, lane = tid & 63;
    const int g = lane >> 4, c = lane & 15;
    const int bid = blockIdx.x;
    const int qtile = bid >> 3, split = bid & 7;  // XCD = bid % 8 = split
    const int tile0 = split * NKV;
    const int rot = ((qtile >> 5) << 4) | ((qtile & 3) << 2);  // stagger offset
    const int othr = tid * 16;
    const int kbase = ((lane & 15) << 6) | ((lane >> 4) << 4);  // c*64 + g*16
    const int vbase = lane << 4;

#define TILE_AT(k) (tile0 + (((k) + rot) & (NKV - 1)))
#define STAGE_KV(k, kslot, vslot)                                                  \
    {                                                                              \
        const char* Kt = (const char*)Kimg + (size_t)TILE_AT(k) * KTILE_BYTES;     \
        const char* Vt = (const char*)Vimg + (size_t)TILE_AT(k) * VTILE_BYTES;     \
        _Pragma("unroll") for (int i = 0; i < 4; ++i) {                            \
            GLOAD_LDS16(Kt + i * 4096 + othr, sK + (kslot)*16384 + i * 4096 + othr); \
            GLOAD_LDS16(Vt + i * 4096 + othr, sV + (vslot)*16384 + i * 4096 + othr); \
        }                                                                          \
    }

    // ---- Q B-fragments ----
    f16x8 qf[2][8];
    {
        const size_t qrow0 = (size_t)qtile * QBLK + wave * 32 + c;
#pragma unroll
        for (int mi = 0; mi < 2; ++mi)
#pragma unroll
            for (int ks = 0; ks < 8; ++ks)
                qf[mi][ks] =
                    *(const f16x8*)(Qh + (qrow0 + mi * 16) * D_DIM + (ks * 4 + g) * 8);
    }
    asm volatile("s_waitcnt vmcnt(0)" ::: "memory");  // Q out of vmcnt counting

    f32x4 acc[2][16];
#pragma unroll
    for (int mi = 0; mi < 2; ++mi)
#pragma unroll
        for (int dt = 0; dt < 16; ++dt) acc[mi][dt] = (f32x4){0.f, 0.f, 0.f, 0.f};
    float m[2] = {-1e30f, -1e30f};
    float l[2] = {0.f, 0.f};

    // ---- prologue: stage tiles 0,1; publish 0; QK(0) ----
    STAGE_KV(0, 0, 0);
    STAGE_KV(1, 1, 1);
    asm volatile("s_waitcnt vmcnt(8)" ::: "memory");  // tile0 landed
    __builtin_amdgcn_s_barrier();

    f32x4 st[2][2];
#pragma unroll
    for (int mi = 0; mi < 2; ++mi)
#pragma unroll
        for (int ct = 0; ct < 2; ++ct) st[mi][ct] = (f32x4){0.f, 0.f, 0.f, 0.f};
    __builtin_amdgcn_s_setprio(1);
#pragma unroll
    for (int ks = 0; ks < 8; ++ks) {
        f16x8 kf0 = *(const f16x8*)(sK + ks * 2048 + kbase);
        f16x8 kf1 = *(const f16x8*)(sK + ks * 2048 + 1024 + kbase);
        st[0][0] = MFMA16(kf0, qf[0][ks], st[0][0]);
        st[0][1] = MFMA16(kf1, qf[0][ks], st[0][1]);
        st[1][0] = MFMA16(kf0, qf[1][ks], st[1][0]);
        st[1][1] = MFMA16(kf1, qf[1][ks], st[1][1]);
    }
    __builtin_amdgcn_s_setprio(0);
    __builtin_amdgcn_s_barrier();  // all waves done with QK(0) before K(2)->Kb0

    for (int kt = 0; kt < NKV; ++kt) {
        // stage tile kt+2 (K into Kb[kt&1], V into Vb[(kt+2)%3])
        if (kt + 2 < NKV) {
            STAGE_KV(kt + 2, kt & 1, (kt + 2) % 3);
            asm volatile("s_waitcnt vmcnt(8)" ::: "memory");  // kt+1 landed
        } else {
            asm volatile("s_waitcnt vmcnt(0)" ::: "memory");
        }
        __builtin_amdgcn_s_barrier();  // publish K(kt+1), V(kt+1)

        // ---- QK(kt+1) [MFMA] interleaved by scheduler with softmax(kt) [VALU] ----
        f32x4 stn[2][2];
#pragma unroll
        for (int mi = 0; mi < 2; ++mi)
#pragma unroll
            for (int ct = 0; ct < 2; ++ct) stn[mi][ct] = (f32x4){0.f, 0.f, 0.f, 0.f};
        if (kt + 1 < NKV) {
            const char* sKb = sK + ((kt + 1) & 1) * 16384;
            __builtin_amdgcn_s_setprio(1);
#pragma unroll
            for (int ks = 0; ks < 8; ++ks) {
                f16x8 kf0 = *(const f16x8*)(sKb + ks * 2048 + kbase);
                f16x8 kf1 = *(const f16x8*)(sKb + ks * 2048 + 1024 + kbase);
                stn[0][0] = MFMA16(kf0, qf[0][ks], stn[0][0]);
                stn[0][1] = MFMA16(kf1, qf[0][ks], stn[0][1]);
                stn[1][0] = MFMA16(kf0, qf[1][ks], stn[1][0]);
                stn[1][1] = MFMA16(kf1, qf[1][ks], stn[1][1]);
            }
            __builtin_amdgcn_s_setprio(0);
        }

        // ---- softmax(st = scores(kt)), base-2; pack P in-lane ----
        union PU { unsigned int u[4]; f16x8 v; };
        PU pu[2];
#pragma unroll
        for (int mi = 0; mi < 2; ++mi) {
            float pm = fmaxf(fmaxf(fmaxf(st[mi][0][0], st[mi][0][1]),
                                   fmaxf(st[mi][0][2], st[mi][0][3])),
                             fmaxf(fmaxf(st[mi][1][0], st[mi][1][1]),
                                   fmaxf(st[mi][1][2], st[mi][1][3])));
            if (__any(pm > m[mi] + RESCALE_THR)) {
                pm = fmaxf(pm, __shfl_xor(pm, 16));
                pm = fmaxf(pm, __shfl_xor(pm, 32));
                float mn = fmaxf(m[mi], pm);
                float sc = EXP2(m[mi] - mn);
                m[mi] = mn;
                l[mi] *= sc;
                float fr[4];
#pragma unroll
                for (int r = 0; r < 4; ++r) fr[r] = __shfl(sc, (g << 4) | (g * 4 + r));
#pragma unroll
                for (int dt = 0; dt < 16; ++dt)
#pragma unroll
                    for (int r = 0; r < 4; ++r) acc[mi][dt][r] *= fr[r];
            }
            float rs = 0.f;
#pragma unroll
            for (int ct = 0; ct < 2; ++ct)
#pragma unroll
                for (int r = 0; r < 4; ++r) {
                    float p = EXP2(st[mi][ct][r] - m[mi]);
                    st[mi][ct][r] = p;
                    rs += p;
                }
            l[mi] += rs;  // per-lane partial; reduced at epilogue
            pu[mi].u[0] = __builtin_bit_cast(
                unsigned int, __builtin_amdgcn_cvt_pkrtz(st[mi][0][0], st[mi][0][1]));
            pu[mi].u[1] = __builtin_bit_cast(
                unsigned int, __builtin_amdgcn_cvt_pkrtz(st[mi][0][2], st[mi][0][3]));
            pu[mi].u[2] = __builtin_bit_cast(
                unsigned int, __builtin_amdgcn_cvt_pkrtz(st[mi][1][0], st[mi][1][1]));
            pu[mi].u[3] = __builtin_bit_cast(
                unsigned int, __builtin_amdgcn_cvt_pkrtz(st[mi][1][2], st[mi][1][3]));
        }

        // ---- PV(kt): acc += P'(kt) x V'(kt)  (linear 1KB wave-reads) ----
        {
            const char* sVb = sV + (kt % 3) * 16384;
            __builtin_amdgcn_s_setprio(1);
#pragma unroll
            for (int dt = 0; dt < 16; ++dt) {
                f16x8 vf = *(const f16x8*)(sVb + dt * 1024 + vbase);
                acc[0][dt] = MFMA16(pu[0].v, vf, acc[0][dt]);
                acc[1][dt] = MFMA16(pu[1].v, vf, acc[1][dt]);
            }
            __builtin_amdgcn_s_setprio(0);
        }

        // carry scores(kt+1) into next iteration
#pragma unroll
        for (int mi = 0; mi < 2; ++mi)
#pragma unroll
            for (int ct = 0; ct < 2; ++ct) st[mi][ct] = stn[mi][ct];

        __builtin_amdgcn_s_barrier();  // end: QK(kt+1)/PV(kt) reads done before restage
    }

    // ---- epilogue: unnormalized partial O (f16) + (m,l) ----
    _Float16* Ob = Opart + (size_t)(qtile * TSPLIT + split) * QBLK * D_DIM;
#pragma unroll
    for (int mi = 0; mi < 2; ++mi)
#pragma unroll
        for (int dt = 0; dt < 16; ++dt)
#pragma unroll
            for (int r = 0; r < 4; ++r) {
                int row = wave * 32 + mi * 16 + g * 4 + r;
                int col = dt * 16 + c;
                Ob[(size_t)row * D_DIM + col] = (_Float16)acc[mi][dt][r];
            }
#pragma unroll
    for (int mi = 0; mi < 2; ++mi) {
        l[mi] += __shfl_xor(l[mi], 16);
        l[mi] += __shfl_xor(l[mi], 32);
    }
    if (g == 0) {
        float* mlb = ml + (size_t)((qtile * TSPLIT + split) * QBLK) * 2;
#pragma unroll
        for (int mi = 0; mi < 2; ++mi) {
            int row = wave * 32 + mi * 16 + c;
            mlb[row * 2 + 0] = m[mi];
            mlb[row * 2 + 1] = l[mi];
        }
    }
}

// ---------------- combine TSPLIT partials (base-2 stats) ----------------
__global__ __launch_bounds__(256) void combine_kernel(const _Float16* __restrict__ Opart,
                                                      const float* __restrict__ ml,
                                                      float* __restrict__ out) {
    int r = blockIdx.x;
    int qtile = r >> 7, rl = r & 127;  // QBLK=128
    int d = threadIdx.x;
    float mv[TSPLIT], lv[TSPLIT];
    float M = -1e30f;
#pragma unroll
    for (int s = 0; s < TSPLIT; ++s) {
        const float* mlb = ml + (size_t)((qtile * TSPLIT + s) * QBLK + rl) * 2;
        mv[s] = mlb[0];
        lv[s] = mlb[1];
        M = fmaxf(M, mv[s]);
    }
    float num = 0.f, den = 0.f;
#pragma unroll
    for (int s = 0; s < TSPLIT; ++s) {
        float w = EXP2(mv[s] - M);
        num += w * (float)Opart[((size_t)(qtile * TSPLIT + s) * QBLK + rl) * D_DIM + d];
        den += w * lv[s];
    }
    out[(size_t)r * D_DIM + d] = num / den;
}

extern "C" void kernel_launch(void* const* d_in, const int* in_sizes, int n_in,
                              void* d_out, int out_size, void* d_ws, size_t ws_size,
                              hipStream_t stream) {
    const float* Q = (const float*)d_in[0];
    const float* K = (const float*)d_in[1];
    const float* V = (const float*)d_in[2];
    float* out = (float*)d_out;
    char* ws = (char*)d_ws;

    _Float16* Qh = (_Float16*)ws;                    // 4MB row-major f16 (x log2e)
    _Float16* Kimg = (_Float16*)(ws + (4 << 20));    // 4MB linear-read 32-key tiles
    _Float16* Vimg = (_Float16*)(ws + (8 << 20));    // 4MB linear-read transposed tiles
    _Float16* Opart = (_Float16*)(ws + (12 << 20));  // 32MB f16 partials
    float* ml = (float*)(ws + ((size_t)44 << 20));   // 512KB

    const int n4 = S_LEN * D_DIM / 4;
    const int nchunks = S_LEN * D_DIM / 8;
    cvt_kernel<<<n4 / 256, 256, 0, stream>>>(Q, Qh, n4);
    cvt_swz_kernel<<<nchunks / 256, 256, 0, stream>>>(K, Kimg, nchunks);
    vt_swz_kernel<<<T_LEN / 32, 256, 0, stream>>>(V, Vimg);

    // 512 blocks x 256 thr, 80KB dyn LDS -> 2 blocks/CU; bid&7 = split = XCD id
    attn_kernel<<<NQT * TSPLIT, 256, SMEM_BYTES, stream>>>(Qh, Kimg, Vimg, Opart, ml);
    combine_kernel<<<S_LEN, 256, 0, stream>>>(Opart, ml, out);
}

// Round 12
// 103.276 us; speedup vs baseline: 1.1066x; 1.0420x over previous
//
#include <hip/hip_runtime.h>
#include <hip/hip_fp16.h>

#define S_LEN 8192
#define T_LEN 8192
#define D_DIM 256
#define QBLK 128
#define KVBLK 32
#define TSPLIT 8
#define NKV ((T_LEN / TSPLIT) / KVBLK)  // 32 tiles per block
#define NQT (S_LEN / QBLK)              // 64
#define KTILE_BYTES 16384               // 32 keys x 256 d x 2B (linear-read image)
#define VTILE_BYTES 16384               // 256 d x 32 keys x 2B (linear-read image)
#define RESCALE_THR 6.0f                // log2 domain
#define LOG2E 1.44269504f
// LDS: Kb 2x16KB @0 ; Vb 2x16KB @32768 -> 65536 B -> 2 blocks/CU
#define SMEM_BYTES 65536

typedef _Float16 f16x8 __attribute__((ext_vector_type(8)));
typedef float f32x4 __attribute__((ext_vector_type(4)));

struct h4 { _Float16 h[4]; };

#define GLOAD_LDS16(g, l)                                              \
    __builtin_amdgcn_global_load_lds(                                  \
        (const __attribute__((address_space(1))) void*)(g),            \
        (__attribute__((address_space(3))) void*)(l), 16, 0, 0)

#define MFMA16(a, b, c) __builtin_amdgcn_mfma_f32_16x16x32_f16(a, b, c, 0, 0, 0)

#if __has_builtin(__builtin_amdgcn_exp2f)
#define EXP2(x) __builtin_amdgcn_exp2f(x)
#else
static __device__ __forceinline__ float EXP2(float x) {
    float y;
    asm("v_exp_f32 %0, %1" : "=v"(y) : "v"(x));
    return y;
}
#endif

// ---------------- Q: fp32 -> f16 row-major, pre-scaled by log2(e) ----------------
__global__ __launch_bounds__(256) void cvt_kernel(const float* __restrict__ in,
                                                  _Float16* __restrict__ out, int n4) {
    int i = blockIdx.x * 256 + threadIdx.x;
    if (i < n4) {
        float4 v = ((const float4*)in)[i];
        h4 o;
        o.h[0] = (_Float16)(v.x * LOG2E); o.h[1] = (_Float16)(v.y * LOG2E);
        o.h[2] = (_Float16)(v.z * LOG2E); o.h[3] = (_Float16)(v.w * LOG2E);
        ((h4*)out)[i] = o;
    }
}

// ------- K -> Kimg. Granule (row r, gr) of tile t (gr=dim/8, ks=gr>>2, g=gr&3)
// at ks*2048 + (r>>4)*1024 + (r&15)*64 + g*16 -> QK step reads are contiguous
// 1KB wave-reads (conflict-free, no swizzle VALU). -------
__global__ __launch_bounds__(256) void cvt_swz_kernel(const float* __restrict__ in,
                                                      _Float16* __restrict__ img,
                                                      int nchunks) {
    int id = blockIdx.x * 256 + threadIdx.x;
    if (id >= nchunks) return;
    int row = id >> 5, gr = id & 31;
    int t = row >> 5, r = row & 31;
    float4 a = *(const float4*)(in + (size_t)row * D_DIM + gr * 8);
    float4 b = *(const float4*)(in + (size_t)row * D_DIM + gr * 8 + 4);
    f16x8 o;
    o[0] = (_Float16)a.x; o[1] = (_Float16)a.y; o[2] = (_Float16)a.z; o[3] = (_Float16)a.w;
    o[4] = (_Float16)b.x; o[5] = (_Float16)b.y; o[6] = (_Float16)b.z; o[7] = (_Float16)b.w;
    *(f16x8*)((char*)img + (size_t)t * KTILE_BYTES + (gr >> 2) * 2048 +
              ((r >> 4) << 10) + ((r & 15) << 6) + ((gr & 3) << 4)) = o;
}

// ------- V -> Vimg. Granule (d, gk) holds keys pi(gk*8+j)=(j>>2)*16+gk*4+(j&3),
// at (d>>4)*1024 + gk*256 + (d&15)*16 -> PV read addr = dt*1024 + lane*16. -------
__global__ __launch_bounds__(256) void vt_swz_kernel(const float* __restrict__ V,
                                                     _Float16* __restrict__ Vimg) {
    __shared__ float tile[32][260];
    const int t = blockIdx.x;
#pragma unroll
    for (int i = 0; i < 8; ++i) {
        int idx = i * 256 + threadIdx.x;
        int kr = idx >> 6, c4 = idx & 63;
        float4 v = *(const float4*)(V + ((size_t)t * 32 + kr) * D_DIM + c4 * 4);
        tile[kr][c4 * 4 + 0] = v.x;
        tile[kr][c4 * 4 + 1] = v.y;
        tile[kr][c4 * 4 + 2] = v.z;
        tile[kr][c4 * 4 + 3] = v.w;
    }
    __syncthreads();
#pragma unroll
    for (int i = 0; i < 4; ++i) {
        int gid = i * 256 + threadIdx.x;
        int d = gid >> 2, gk = gid & 3;
        f16x8 o;
#pragma unroll
        for (int j = 0; j < 8; ++j)
            o[j] = (_Float16)tile[(j >> 2) * 16 + gk * 4 + (j & 3)][d];
        *(f16x8*)((char*)Vimg + (size_t)t * VTILE_BYTES + ((d >> 4) << 10) +
                  (gk << 8) + ((d & 15) << 4)) = o;
    }
}

// ------------- flash attention: R9 base, 1-barrier/tile schedule -------------
// 4 waves x 32 q-rows (M_rep=2), dbuf K+V (64KB), 2 blocks/CU.
// Per tile: {lgkmcnt(0); vmcnt(0); barrier} -> stage(kt+1) into slot (kt+1)&1
// -> QK(kt) -> softmax -> PV(kt). Hazards: stage targets the slot last read at
// compute(kt-1), sealed by this barrier; compute(kt) reads the other slot; the
// vmcnt(0) waits on loads issued one full compute phase ago (aged -> ~free).
// Halves the per-tile barrier-convergence cost vs R9 (2 barriers -> 1).
__global__ __launch_bounds__(256, 2) void attn_kernel(
    const _Float16* __restrict__ Qh, const _Float16* __restrict__ Kimg,
    const _Float16* __restrict__ Vimg, _Float16* __restrict__ Opart,
    float* __restrict__ ml) {
    extern __shared__ __align__(16) char smem[];
    char* sK = smem;          // 2 x 16KB
    char* sV = smem + 32768;  // 2 x 16KB
    const int tid = threadIdx.x;
    const int wave = tid >> 6, lane = tid & 63;
    const int g = lane >> 4, c = lane & 15;
    const int bid = blockIdx.x;
    const int qtile = bid >> 3, split = bid & 7;  // XCD = bid % 8 = split
    const int tile0 = split * NKV;
    const int rot = ((qtile >> 5) << 4) | ((qtile & 3) << 2);  // stagger offset
    const int othr = tid * 16;
    const int kbase = ((lane & 15) << 6) | ((lane >> 4) << 4);  // c*64 + g*16
    const int vbase = lane << 4;

#define TILE_AT(k) (tile0 + (((k) + rot) & (NKV - 1)))
#define STAGE_KV(k, slot)                                                          \
    {                                                                              \
        const char* Kt = (const char*)Kimg + (size_t)TILE_AT(k) * KTILE_BYTES;     \
        const char* Vt = (const char*)Vimg + (size_t)TILE_AT(k) * VTILE_BYTES;     \
        _Pragma("unroll") for (int i = 0; i < 4; ++i) {                            \
            GLOAD_LDS16(Kt + i * 4096 + othr, sK + (slot)*16384 + i * 4096 + othr); \
            GLOAD_LDS16(Vt + i * 4096 + othr, sV + (slot)*16384 + i * 4096 + othr); \
        }                                                                          \
    }

    // ---- Q B-fragments: B[n=q=c][k = ks*32 + g*8 + j] ----
    f16x8 qf[2][8];
    {
        const size_t qrow0 = (size_t)qtile * QBLK + wave * 32 + c;
#pragma unroll
        for (int mi = 0; mi < 2; ++mi)
#pragma unroll
            for (int ks = 0; ks < 8; ++ks)
                qf[mi][ks] =
                    *(const f16x8*)(Qh + (qrow0 + mi * 16) * D_DIM + (ks * 4 + g) * 8);
    }

    f32x4 acc[2][16];
#pragma unroll
    for (int mi = 0; mi < 2; ++mi)
#pragma unroll
        for (int dt = 0; dt < 16; ++dt) acc[mi][dt] = (f32x4){0.f, 0.f, 0.f, 0.f};
    float m[2] = {-1e30f, -1e30f};
    float l[2] = {0.f, 0.f};  // per-lane partials, reduced at epilogue

    // ---- prologue: stage tile 0 into slot 0 ----
    STAGE_KV(0, 0);

    for (int kt = 0; kt < NKV; ++kt) {
        asm volatile("s_waitcnt lgkmcnt(0)" ::: "memory");
        asm volatile("s_waitcnt vmcnt(0)" ::: "memory");  // stage(kt) landed (aged)
        __builtin_amdgcn_s_barrier();  // K/V(kt) visible; all prior-iter reads done

        // stage(kt+1) into the opposite slot: flies under compute(kt)
        if (kt + 1 < NKV) STAGE_KV(kt + 1, (kt + 1) & 1);

        const char* sKb = sK + (kt & 1) * 16384;
        const char* sVb = sV + (kt & 1) * 16384;

        // ---- QK^T swapped: st[mi][ct] = S^T[key=ct*16+g*4+r][q=mi*16+c] ----
        f32x4 st[2][2];
#pragma unroll
        for (int mi = 0; mi < 2; ++mi)
#pragma unroll
            for (int ct = 0; ct < 2; ++ct) st[mi][ct] = (f32x4){0.f, 0.f, 0.f, 0.f};
        __builtin_amdgcn_s_setprio(1);
#pragma unroll
        for (int ks = 0; ks < 8; ++ks) {
            f16x8 kf0 = *(const f16x8*)(sKb + ks * 2048 + kbase);
            f16x8 kf1 = *(const f16x8*)(sKb + ks * 2048 + 1024 + kbase);
            st[0][0] = MFMA16(kf0, qf[0][ks], st[0][0]);
            st[0][1] = MFMA16(kf1, qf[0][ks], st[0][1]);
            st[1][0] = MFMA16(kf0, qf[1][ks], st[1][0]);
            st[1][1] = MFMA16(kf1, qf[1][ks], st[1][1]);
        }
        __builtin_amdgcn_s_setprio(0);

        // ---- online softmax, base-2 (q-row = c; keys spread over g,ct,r) ----
        union PU { unsigned int u[4]; f16x8 v; };
        PU pu[2];
#pragma unroll
        for (int mi = 0; mi < 2; ++mi) {
            float pm = fmaxf(fmaxf(fmaxf(st[mi][0][0], st[mi][0][1]),
                                   fmaxf(st[mi][0][2], st[mi][0][3])),
                             fmaxf(fmaxf(st[mi][1][0], st[mi][1][1]),
                                   fmaxf(st[mi][1][2], st[mi][1][3])));
            if (__any(pm > m[mi] + RESCALE_THR)) {
                pm = fmaxf(pm, __shfl_xor(pm, 16));
                pm = fmaxf(pm, __shfl_xor(pm, 32));
                float mn = fmaxf(m[mi], pm);
                float sc = EXP2(m[mi] - mn);
                m[mi] = mn;
                l[mi] *= sc;
                float fr[4];
#pragma unroll
                for (int r = 0; r < 4; ++r) fr[r] = __shfl(sc, (g << 4) | (g * 4 + r));
#pragma unroll
                for (int dt = 0; dt < 16; ++dt)
#pragma unroll
                    for (int r = 0; r < 4; ++r) acc[mi][dt][r] *= fr[r];
            }
            float rs = 0.f;
#pragma unroll
            for (int ct = 0; ct < 2; ++ct)
#pragma unroll
                for (int r = 0; r < 4; ++r) {
                    float p = EXP2(st[mi][ct][r] - m[mi]);
                    st[mi][ct][r] = p;
                    rs += p;
                }
            l[mi] += rs;  // per-lane partial; reduced at epilogue
            // pack P in-lane: A'[q=c][kslot g*8+j], pi(g*8+j)=(j>>2)*16+g*4+(j&3)
            pu[mi].u[0] = __builtin_bit_cast(
                unsigned int, __builtin_amdgcn_cvt_pkrtz(st[mi][0][0], st[mi][0][1]));
            pu[mi].u[1] = __builtin_bit_cast(
                unsigned int, __builtin_amdgcn_cvt_pkrtz(st[mi][0][2], st[mi][0][3]));
            pu[mi].u[2] = __builtin_bit_cast(
                unsigned int, __builtin_amdgcn_cvt_pkrtz(st[mi][1][0], st[mi][1][1]));
            pu[mi].u[3] = __builtin_bit_cast(
                unsigned int, __builtin_amdgcn_cvt_pkrtz(st[mi][1][2], st[mi][1][3]));
        }

        // ---- PV(kt): acc += P' x V'  (fused: one vf read feeds both mi) ----
        __builtin_amdgcn_s_setprio(1);
#pragma unroll
        for (int dt = 0; dt < 16; ++dt) {
            f16x8 vf = *(const f16x8*)(sVb + dt * 1024 + vbase);
            acc[0][dt] = MFMA16(pu[0].v, vf, acc[0][dt]);
            acc[1][dt] = MFMA16(pu[1].v, vf, acc[1][dt]);
        }
        __builtin_amdgcn_s_setprio(0);
    }

    // ---- epilogue: unnormalized partial O (f16) + (m,l) ----
    _Float16* Ob = Opart + (size_t)(qtile * TSPLIT + split) * QBLK * D_DIM;
#pragma unroll
    for (int mi = 0; mi < 2; ++mi)
#pragma unroll
        for (int dt = 0; dt < 16; ++dt)
#pragma unroll
            for (int r = 0; r < 4; ++r) {
                int row = wave * 32 + mi * 16 + g * 4 + r;
                int col = dt * 16 + c;
                Ob[(size_t)row * D_DIM + col] = (_Float16)acc[mi][dt][r];
            }
#pragma unroll
    for (int mi = 0; mi < 2; ++mi) {
        l[mi] += __shfl_xor(l[mi], 16);
        l[mi] += __shfl_xor(l[mi], 32);
    }
    if (g == 0) {
        float* mlb = ml + (size_t)((qtile * TSPLIT + split) * QBLK) * 2;
#pragma unroll
        for (int mi = 0; mi < 2; ++mi) {
            int row = wave * 32 + mi * 16 + c;
            mlb[row * 2 + 0] = m[mi];
            mlb[row * 2 + 1] = l[mi];
        }
    }
}

// ---------------- combine TSPLIT partials (base-2 stats) ----------------
__global__ __launch_bounds__(256) void combine_kernel(const _Float16* __restrict__ Opart,
                                                      const float* __restrict__ ml,
                                                      float* __restrict__ out) {
    int r = blockIdx.x;
    int qtile = r >> 7, rl = r & 127;  // QBLK=128
    int d = threadIdx.x;
    float mv[TSPLIT], lv[TSPLIT];
    float M = -1e30f;
#pragma unroll
    for (int s = 0; s < TSPLIT; ++s) {
        const float* mlb = ml + (size_t)((qtile * TSPLIT + s) * QBLK + rl) * 2;
        mv[s] = mlb[0];
        lv[s] = mlb[1];
        M = fmaxf(M, mv[s]);
    }
    float num = 0.f, den = 0.f;
#pragma unroll
    for (int s = 0; s < TSPLIT; ++s) {
        float w = EXP2(mv[s] - M);
        num += w * (float)Opart[((size_t)(qtile * TSPLIT + s) * QBLK + rl) * D_DIM + d];
        den += w * lv[s];
    }
    out[(size_t)r * D_DIM + d] = num / den;
}

extern "C" void kernel_launch(void* const* d_in, const int* in_sizes, int n_in,
                              void* d_out, int out_size, void* d_ws, size_t ws_size,
                              hipStream_t stream) {
    const float* Q = (const float*)d_in[0];
    const float* K = (const float*)d_in[1];
    const float* V = (const float*)d_in[2];
    float* out = (float*)d_out;
    char* ws = (char*)d_ws;

    _Float16* Qh = (_Float16*)ws;                    // 4MB row-major f16 (x log2e)
    _Float16* Kimg = (_Float16*)(ws + (4 << 20));    // 4MB linear-read 32-key tiles
    _Float16* Vimg = (_Float16*)(ws + (8 << 20));    // 4MB linear-read transposed tiles
    _Float16* Opart = (_Float16*)(ws + (12 << 20));  // 32MB f16 partials
    float* ml = (float*)(ws + ((size_t)44 << 20));   // 512KB

    const int n4 = S_LEN * D_DIM / 4;
    const int nchunks = S_LEN * D_DIM / 8;
    cvt_kernel<<<n4 / 256, 256, 0, stream>>>(Q, Qh, n4);
    cvt_swz_kernel<<<nchunks / 256, 256, 0, stream>>>(K, Kimg, nchunks);
    vt_swz_kernel<<<T_LEN / 32, 256, 0, stream>>>(V, Vimg);

    // 512 blocks x 256 thr, 64KB dyn LDS -> 2 blocks/CU; bid&7 = split = XCD id
    attn_kernel<<<NQT * TSPLIT, 256, SMEM_BYTES, stream>>>(Qh, Kimg, Vimg, Opart, ml);
    combine_kernel<<<S_LEN, 256, 0, stream>>>(Opart, ml, out);
}